// Round 4
// baseline (1353.989 us; speedup 1.0000x reference)
//
#include <hip/hip_runtime.h>
#include <math.h>

// VQ nearest-code (argmax quirk preserved): out[t] = codebook[argmax_k(e_sq[k] - 2*x_t.c_k)]
// Fused split-f16 MFMA GEMM + running argmax + gather. No workspace use.

#define NTOK   32768
#define NCODE  8192
#define KD     512
#define BT     128     // tokens per block
#define BC     256     // codes per tile
#define BK     32      // k per step
#define NTILE  (NCODE/BC)   // 32
#define NK     (KD/BK)      // 16

typedef float  f32x4 __attribute__((ext_vector_type(4)));
typedef __fp16 f16x8 __attribute__((ext_vector_type(8)));
typedef __fp16 f16x2 __attribute__((ext_vector_type(2)));

__device__ __forceinline__ f16x2 cvt_pk_rtz(float a, float b) {
    return __builtin_amdgcn_cvt_pkrtz(a, b);
}

// ushort-unit offset into a [rows][32] f16 tile (64B pitch), 16B-slot XOR swizzle.
// Conflict-free for both staging writes and b128 fragment reads.
__device__ __forceinline__ int lds_off(int row, int kbase) {
    int slot = kbase >> 3;            // 0..3
    int sw   = (row >> 1) & 3;
    return row * 32 + ((slot ^ sw) << 3);
}

// split v = hi + lo (f16 RTZ); 8 elems from two f32x4
__device__ __forceinline__ void cvt_split8(f32x4 u0, f32x4 u1, f16x8& H, f16x8& L) {
    f16x2 h0 = cvt_pk_rtz(u0[0], u0[1]);
    f16x2 h1 = cvt_pk_rtz(u0[2], u0[3]);
    f16x2 h2 = cvt_pk_rtz(u1[0], u1[1]);
    f16x2 h3 = cvt_pk_rtz(u1[2], u1[3]);
    f16x2 l0 = cvt_pk_rtz(u0[0] - (float)h0[0], u0[1] - (float)h0[1]);
    f16x2 l1 = cvt_pk_rtz(u0[2] - (float)h1[0], u0[3] - (float)h1[1]);
    f16x2 l2 = cvt_pk_rtz(u1[0] - (float)h2[0], u1[1] - (float)h2[1]);
    f16x2 l3 = cvt_pk_rtz(u1[2] - (float)h3[0], u1[3] - (float)h3[1]);
    H[0]=h0[0]; H[1]=h0[1]; H[2]=h1[0]; H[3]=h1[1];
    H[4]=h2[0]; H[5]=h2[1]; H[6]=h3[0]; H[7]=h3[1];
    L[0]=l0[0]; L[1]=l0[1]; L[2]=l1[0]; L[3]=l1[1];
    L[4]=l2[0]; L[5]=l2[1]; L[6]=l3[0]; L[7]=l3[1];
}

__global__ __launch_bounds__(256, 2)
void vq_argmax_gather(const float* __restrict__ x,
                      const float* __restrict__ cb,
                      float* __restrict__ out)
{
    // A = codebook tile (M=codes), B = x tile (N=tokens), both [row][k] f16 hi/lo
    __shared__ __fp16 sAh[BC * 32];
    __shared__ __fp16 sAl[BC * 32];
    __shared__ __fp16 sBh[BT * 32];
    __shared__ __fp16 sBl[BT * 32];
    __shared__ float  sEsq[BC];
    __shared__ float  sMrg[2][BT][2];   // [wm][token][{val, idx-bits}]
    __shared__ int    sIdx[BT];

    const int tid  = threadIdx.x;
    const int lane = tid & 63;
    const int wid  = tid >> 6;      // 0..3
    const int wm   = wid >> 1;      // code half (0/1)
    const int wn   = wid & 1;       // token half (0/1)
    const int g    = lane >> 4;     // 0..3
    const int lr   = lane & 15;
    const int tok0 = blockIdx.x * BT;

    // fragment read bases (row+16 adds exactly 512 ushorts; swizzle invariant mod 16 rows)
    const int offA0 = lds_off(wm * 128 + lr, g * 8);
    const int offB0 = lds_off(wn * 64  + lr, g * 8);

    // staging: thread t stages codebook row t of the tile (32 f32/kstep),
    //          and x row t>>1, k-half t&1 (16 f32/kstep)
    const float* aSrc = cb + (size_t)tid * KD;
    const int brow = tid >> 1, bkh = tid & 1;
    const float* bSrc = x + (size_t)(tok0 + brow) * KD + bkh * 16;

    const int awBase = tid * 32,  swA = (tid >> 1) & 3;
    const int bwBase = brow * 32, swB = (brow >> 1) & 3;

    f32x4 ar[8], br[4];
    {   // prologue loads (tile 0, kstep 0)
        const f32x4* ap = (const f32x4*)aSrc;
#pragma unroll
        for (int j = 0; j < 8; ++j) ar[j] = ap[j];
        const f32x4* bp = (const f32x4*)bSrc;
#pragma unroll
        for (int j = 0; j < 4; ++j) br[j] = bp[j];
    }

    float bv[4]; int bi[4];
#pragma unroll
    for (int nf = 0; nf < 4; ++nf) { bv[nf] = -INFINITY; bi[nf] = 0; }

    f32x4 acc[8][4];

    for (int nt = 0; nt < NTILE; ++nt) {
#pragma unroll
        for (int mf = 0; mf < 8; ++mf)
#pragma unroll
            for (int nf = 0; nf < 4; ++nf)
                acc[mf][nf] = (f32x4){0.f, 0.f, 0.f, 0.f};

        f32x4 esqv = {0.f, 0.f, 0.f, 0.f};

        for (int ks = 0; ks < NK; ++ks) {
            // ---- stage A (codes): convert + LDS write + e_sq accumulate ----
#pragma unroll
            for (int s = 0; s < 4; ++s) {
                f32x4 u0 = ar[2*s], u1 = ar[2*s+1];
                esqv += u0 * u0;
                esqv += u1 * u1;
                f16x8 H, L;
                cvt_split8(u0, u1, H, L);
                const int aw = awBase + ((s ^ swA) << 3);
                *(f16x8*)&sAh[aw] = H;
                *(f16x8*)&sAl[aw] = L;
            }
            // ---- stage B (tokens) ----
#pragma unroll
            for (int s = 0; s < 2; ++s) {
                f32x4 u0 = br[2*s], u1 = br[2*s+1];
                f16x8 H, L;
                cvt_split8(u0, u1, H, L);
                const int slot = 2 * bkh + s;
                const int bw = bwBase + ((slot ^ swB) << 3);
                *(f16x8*)&sBh[bw] = H;
                *(f16x8*)&sBl[bw] = L;
            }
            if (ks == NK - 1) sEsq[tid] = esqv[0] + esqv[1] + esqv[2] + esqv[3];

            // ---- prefetch next kstep/tile (hides L2/L3 latency under MFMA) ----
            if (!(nt == NTILE - 1 && ks == NK - 1)) {
                const int nnt = (ks == NK - 1) ? nt + 1 : nt;
                const int nks = (ks == NK - 1) ? 0 : ks + 1;
                const f32x4* ap = (const f32x4*)(aSrc + (size_t)nnt * BC * KD + nks * BK);
#pragma unroll
                for (int j = 0; j < 8; ++j) ar[j] = ap[j];
                const f32x4* bp = (const f32x4*)(bSrc + nks * BK);
#pragma unroll
                for (int j = 0; j < 4; ++j) br[j] = bp[j];
            }

            __syncthreads();

            // ---- MFMA: 128 per wave-kstep (hh, hl, lh, ll into same acc) ----
            f16x8 bh[4], bl[4];
#pragma unroll
            for (int nf = 0; nf < 4; ++nf) {
                bh[nf] = *(const f16x8*)&sBh[offB0 + nf * 512];
                bl[nf] = *(const f16x8*)&sBl[offB0 + nf * 512];
            }
#pragma unroll
            for (int mf = 0; mf < 8; ++mf) {
                f16x8 ah = *(const f16x8*)&sAh[offA0 + mf * 512];
                f16x8 al = *(const f16x8*)&sAl[offA0 + mf * 512];
#pragma unroll
                for (int nf = 0; nf < 4; ++nf)
                    acc[mf][nf] = __builtin_amdgcn_mfma_f32_16x16x32_f16(ah, bh[nf], acc[mf][nf], 0, 0, 0);
#pragma unroll
                for (int nf = 0; nf < 4; ++nf)
                    acc[mf][nf] = __builtin_amdgcn_mfma_f32_16x16x32_f16(ah, bl[nf], acc[mf][nf], 0, 0, 0);
#pragma unroll
                for (int nf = 0; nf < 4; ++nf)
                    acc[mf][nf] = __builtin_amdgcn_mfma_f32_16x16x32_f16(al, bh[nf], acc[mf][nf], 0, 0, 0);
#pragma unroll
                for (int nf = 0; nf < 4; ++nf)
                    acc[mf][nf] = __builtin_amdgcn_mfma_f32_16x16x32_f16(al, bl[nf], acc[mf][nf], 0, 0, 0);
            }
            __syncthreads();
        }

        // ---- epilogue: score = e_sq - 2*(x.c); running argmax (first-max tiebreak) ----
        const int codeTileBase = nt * BC;
#pragma unroll
        for (int mf = 0; mf < 8; ++mf) {
            const int cl = wm * 128 + mf * 16 + g * 4;
            const f32x4 es = *(const f32x4*)&sEsq[cl];
            const int cbase = codeTileBase + cl;
#pragma unroll
            for (int r = 0; r < 4; ++r) {
#pragma unroll
                for (int nf = 0; nf < 4; ++nf) {
                    const float s = fmaf(-2.0f, acc[mf][nf][r], es[r]);  // dist = e_sq - 2*x.c (+x_sq, common)
                    if (s > bv[nf]) { bv[nf] = s; bi[nf] = cbase + r; }
                }
            }
        }
    }

    // ---- cross-lane reduce over the 4 row-groups (lanes sharing lane&15) ----
#pragma unroll
    for (int nf = 0; nf < 4; ++nf) {
#pragma unroll
        for (int d = 16; d <= 32; d <<= 1) {
            const float ov = __shfl_xor(bv[nf], d, 64);
            const int   oi = __shfl_xor(bi[nf], d, 64);
            if (ov > bv[nf] || (ov == bv[nf] && oi < bi[nf])) { bv[nf] = ov; bi[nf] = oi; }
        }
    }
    if (g == 0) {
#pragma unroll
        for (int nf = 0; nf < 4; ++nf) {
            const int tl = wn * 64 + nf * 16 + lr;
            sMrg[wm][tl][0] = bv[nf];
            sMrg[wm][tl][1] = __int_as_float(bi[nf]);
        }
    }
    __syncthreads();

    // ---- cross-wave (code-half) merge ----
    if (tid < BT) {
        const float v0 = sMrg[0][tid][0];
        const float v1 = sMrg[1][tid][0];
        const int   i0 = __float_as_int(sMrg[0][tid][1]);
        const int   i1 = __float_as_int(sMrg[1][tid][1]);
        sIdx[tid] = (v1 > v0 || (v1 == v0 && i1 < i0)) ? i1 : i0;
    }
    __syncthreads();

    // ---- gather: out[token] = codebook[best_idx] (exact f32 copy) ----
    const f32x4* cb4  = (const f32x4*)cb;
    f32x4*       out4 = (f32x4*)out;
    for (int i = tid; i < BT * (KD / 4); i += 256) {
        const int r = i >> 7;       // KD/4 = 128 vec4 per row
        const int c = i & 127;
        out4[(size_t)(tok0 + r) * 128 + c] = cb4[(size_t)sIdx[r] * 128 + c];
    }
}

extern "C" void kernel_launch(void* const* d_in, const int* in_sizes, int n_in,
                              void* d_out, int out_size, void* d_ws, size_t ws_size,
                              hipStream_t stream) {
    const float* x   = (const float*)d_in[0];   // [32768, 512] f32
    const float* cb  = (const float*)d_in[1];   // [8192, 512] f32
    float*       out = (float*)d_out;           // [32768, 512] f32
    (void)in_sizes; (void)n_in; (void)d_ws; (void)ws_size; (void)out_size;

    vq_argmax_gather<<<dim3(NTOK / BT), dim3(256), 0, stream>>>(x, cb, out);
}

// Round 5
// 1217.948 us; speedup vs baseline: 1.1117x; 1.1117x over previous
//
#include <hip/hip_runtime.h>
#include <math.h>

// VQ nearest-code (argmax quirk preserved): out[t] = codebook[argmax_k(e_sq[k] - 2*x_t.c_k)]
// Fused split-f16 MFMA GEMM (3-product: hh+hl+lh) + running argmax + gather.
// R5: BT=64 -> 512 blocks (2/CU) for cross-block stall overlap; dropped lo*lo MFMA.

#define NTOK   32768
#define NCODE  8192
#define KD     512
#define BT     64      // tokens per block
#define BC     256     // codes per tile
#define BK     32      // k per step
#define NTILE  (NCODE/BC)   // 32
#define NK     (KD/BK)      // 16

typedef float  f32x4 __attribute__((ext_vector_type(4)));
typedef __fp16 f16x8 __attribute__((ext_vector_type(8)));
typedef __fp16 f16x2 __attribute__((ext_vector_type(2)));

__device__ __forceinline__ f16x2 cvt_pk_rtz(float a, float b) {
    return __builtin_amdgcn_cvt_pkrtz(a, b);
}

// ushort-unit offset into a [rows][32] f16 tile (64B pitch), 16B-slot XOR swizzle.
// Conflict-free for staging writes and b128 fragment reads; invariant under row+=16.
__device__ __forceinline__ int lds_off(int row, int kbase) {
    int slot = kbase >> 3;            // 0..3
    int sw   = (row >> 1) & 3;
    return row * 32 + ((slot ^ sw) << 3);
}

// split v = hi + lo (f16 RTZ); 8 elems from two f32x4
__device__ __forceinline__ void cvt_split8(f32x4 u0, f32x4 u1, f16x8& H, f16x8& L) {
    f16x2 h0 = cvt_pk_rtz(u0[0], u0[1]);
    f16x2 h1 = cvt_pk_rtz(u0[2], u0[3]);
    f16x2 h2 = cvt_pk_rtz(u1[0], u1[1]);
    f16x2 h3 = cvt_pk_rtz(u1[2], u1[3]);
    f16x2 l0 = cvt_pk_rtz(u0[0] - (float)h0[0], u0[1] - (float)h0[1]);
    f16x2 l1 = cvt_pk_rtz(u0[2] - (float)h1[0], u0[3] - (float)h1[1]);
    f16x2 l2 = cvt_pk_rtz(u1[0] - (float)h2[0], u1[1] - (float)h2[1]);
    f16x2 l3 = cvt_pk_rtz(u1[2] - (float)h3[0], u1[3] - (float)h3[1]);
    H[0]=h0[0]; H[1]=h0[1]; H[2]=h1[0]; H[3]=h1[1];
    H[4]=h2[0]; H[5]=h2[1]; H[6]=h3[0]; H[7]=h3[1];
    L[0]=l0[0]; L[1]=l0[1]; L[2]=l1[0]; L[3]=l1[1];
    L[4]=l2[0]; L[5]=l2[1]; L[6]=l3[0]; L[7]=l3[1];
}

__global__ __launch_bounds__(256, 2)
void vq_argmax_gather(const float* __restrict__ x,
                      const float* __restrict__ cb,
                      float* __restrict__ out)
{
    // A = codebook tile (M=codes, 256 rows), B = x tile (N=tokens, 64 rows)
    __shared__ __fp16 sAh[BC * 32];
    __shared__ __fp16 sAl[BC * 32];
    __shared__ __fp16 sBh[BT * 32];
    __shared__ __fp16 sBl[BT * 32];
    __shared__ float  sEsq[BC];
    __shared__ float  sMrg[4][BT][2];   // [wave][token][{val, idx-bits}]
    __shared__ int    sIdx[BT];

    const int tid  = threadIdx.x;
    const int lane = tid & 63;
    const int wid  = tid >> 6;      // 0..3 -> code quarter of the tile
    const int g    = lane >> 4;     // 0..3
    const int lr   = lane & 15;
    const int tok0 = blockIdx.x * BT;

    // fragment read bases (mf/nf step = 16 rows = +512 ushorts, swizzle-invariant)
    const int offA0 = lds_off(wid * 64 + lr, g * 8);
    const int offB0 = lds_off(lr,           g * 8);

    // staging: thread t stages codebook row t of the tile (32 f32/kstep),
    //          and x row t>>2, k-quarter t&3 (8 f32/kstep)
    const float* aSrc = cb + (size_t)tid * KD;
    const int brow = tid >> 2, bq = tid & 3;
    const float* bSrc = x + (size_t)(tok0 + brow) * KD + bq * 8;

    const int awBase = tid * 32,  swA = (tid >> 1) & 3;
    const int bwOff  = brow * 32 + (((bq ^ ((brow >> 1) & 3))) << 3);

    f32x4 ar[8], br[2];
    {   // prologue loads (tile 0, kstep 0)
        const f32x4* ap = (const f32x4*)aSrc;
#pragma unroll
        for (int j = 0; j < 8; ++j) ar[j] = ap[j];
        const f32x4* bp = (const f32x4*)bSrc;
        br[0] = bp[0]; br[1] = bp[1];
    }

    float bv[4]; int bi[4];
#pragma unroll
    for (int nf = 0; nf < 4; ++nf) { bv[nf] = -INFINITY; bi[nf] = 0; }

    f32x4 acc[4][4];

    for (int nt = 0; nt < NTILE; ++nt) {
#pragma unroll
        for (int mf = 0; mf < 4; ++mf)
#pragma unroll
            for (int nf = 0; nf < 4; ++nf)
                acc[mf][nf] = (f32x4){0.f, 0.f, 0.f, 0.f};

        f32x4 esqv = {0.f, 0.f, 0.f, 0.f};

        for (int ks = 0; ks < NK; ++ks) {
            // ---- stage A (codes): convert + LDS write + e_sq accumulate ----
#pragma unroll
            for (int s = 0; s < 4; ++s) {
                f32x4 u0 = ar[2*s], u1 = ar[2*s+1];
                esqv += u0 * u0;
                esqv += u1 * u1;
                f16x8 H, L;
                cvt_split8(u0, u1, H, L);
                const int aw = awBase + ((s ^ swA) << 3);
                *(f16x8*)&sAh[aw] = H;
                *(f16x8*)&sAl[aw] = L;
            }
            // ---- stage B (tokens): one 16B slot each of hi/lo ----
            {
                f16x8 H, L;
                cvt_split8(br[0], br[1], H, L);
                *(f16x8*)&sBh[bwOff] = H;
                *(f16x8*)&sBl[bwOff] = L;
            }
            if (ks == NK - 1) sEsq[tid] = esqv[0] + esqv[1] + esqv[2] + esqv[3];

            // ---- prefetch next kstep/tile (hides L2/L3 latency under MFMA) ----
            if (!(nt == NTILE - 1 && ks == NK - 1)) {
                const int nnt = (ks == NK - 1) ? nt + 1 : nt;
                const int nks = (ks == NK - 1) ? 0 : ks + 1;
                const f32x4* ap = (const f32x4*)(aSrc + (size_t)nnt * BC * KD + nks * BK);
#pragma unroll
                for (int j = 0; j < 8; ++j) ar[j] = ap[j];
                const f32x4* bp = (const f32x4*)(bSrc + nks * BK);
                br[0] = bp[0]; br[1] = bp[1];
            }

            __syncthreads();

            // ---- MFMA: 48 per wave-kstep (hh, hl, lh into same acc) ----
            f16x8 bh[4], bl[4];
#pragma unroll
            for (int nf = 0; nf < 4; ++nf) {
                bh[nf] = *(const f16x8*)&sBh[offB0 + nf * 512];
                bl[nf] = *(const f16x8*)&sBl[offB0 + nf * 512];
            }
#pragma unroll
            for (int mf = 0; mf < 4; ++mf) {
                f16x8 ah = *(const f16x8*)&sAh[offA0 + mf * 512];
                f16x8 al = *(const f16x8*)&sAl[offA0 + mf * 512];
#pragma unroll
                for (int nf = 0; nf < 4; ++nf)
                    acc[mf][nf] = __builtin_amdgcn_mfma_f32_16x16x32_f16(ah, bh[nf], acc[mf][nf], 0, 0, 0);
#pragma unroll
                for (int nf = 0; nf < 4; ++nf)
                    acc[mf][nf] = __builtin_amdgcn_mfma_f32_16x16x32_f16(ah, bl[nf], acc[mf][nf], 0, 0, 0);
#pragma unroll
                for (int nf = 0; nf < 4; ++nf)
                    acc[mf][nf] = __builtin_amdgcn_mfma_f32_16x16x32_f16(al, bh[nf], acc[mf][nf], 0, 0, 0);
            }
            __syncthreads();
        }

        // ---- epilogue: score = e_sq - 2*(x.c); running argmax (first-max tiebreak) ----
        const int codeTileBase = nt * BC;
#pragma unroll
        for (int mf = 0; mf < 4; ++mf) {
            const int cl = wid * 64 + mf * 16 + g * 4;
            const f32x4 es = *(const f32x4*)&sEsq[cl];
            const int cbase = codeTileBase + cl;
#pragma unroll
            for (int r = 0; r < 4; ++r) {
#pragma unroll
                for (int nf = 0; nf < 4; ++nf) {
                    const float s = fmaf(-2.0f, acc[mf][nf][r], es[r]);
                    if (s > bv[nf]) { bv[nf] = s; bi[nf] = cbase + r; }
                }
            }
        }
    }

    // ---- cross-lane reduce over the 4 row-groups (lanes sharing lane&15) ----
#pragma unroll
    for (int nf = 0; nf < 4; ++nf) {
#pragma unroll
        for (int d = 16; d <= 32; d <<= 1) {
            const float ov = __shfl_xor(bv[nf], d, 64);
            const int   oi = __shfl_xor(bi[nf], d, 64);
            if (ov > bv[nf] || (ov == bv[nf] && oi < bi[nf])) { bv[nf] = ov; bi[nf] = oi; }
        }
    }
    if (g == 0) {
#pragma unroll
        for (int nf = 0; nf < 4; ++nf) {
            const int tl = nf * 16 + lr;
            sMrg[wid][tl][0] = bv[nf];
            sMrg[wid][tl][1] = __int_as_float(bi[nf]);
        }
    }
    __syncthreads();

    // ---- cross-wave (code-quarter) merge, lowest-index tiebreak ----
    if (tid < BT) {
        float v = sMrg[0][tid][0];
        int   idx = __float_as_int(sMrg[0][tid][1]);
#pragma unroll
        for (int w = 1; w < 4; ++w) {
            const float vw = sMrg[w][tid][0];
            const int   iw = __float_as_int(sMrg[w][tid][1]);
            if (vw > v || (vw == v && iw < idx)) { v = vw; idx = iw; }
        }
        sIdx[tid] = idx;
    }
    __syncthreads();

    // ---- gather: out[token] = codebook[best_idx] (exact f32 copy) ----
    const f32x4* cb4  = (const f32x4*)cb;
    f32x4*       out4 = (f32x4*)out;
    for (int i = tid; i < BT * (KD / 4); i += 256) {
        const int r = i >> 7;       // KD/4 = 128 vec4 per row
        const int c = i & 127;
        out4[(size_t)(tok0 + r) * 128 + c] = cb4[(size_t)sIdx[r] * 128 + c];
    }
}

extern "C" void kernel_launch(void* const* d_in, const int* in_sizes, int n_in,
                              void* d_out, int out_size, void* d_ws, size_t ws_size,
                              hipStream_t stream) {
    const float* x   = (const float*)d_in[0];   // [32768, 512] f32
    const float* cb  = (const float*)d_in[1];   // [8192, 512] f32
    float*       out = (float*)d_out;           // [32768, 512] f32
    (void)in_sizes; (void)n_in; (void)d_ws; (void)ws_size; (void)out_size;

    vq_argmax_gather<<<dim3(NTOK / BT), dim3(256), 0, stream>>>(x, cb, out);
}